// Round 3
// baseline (326.245 us; speedup 1.0000x reference)
//
#include <hip/hip_runtime.h>
#include <stdint.h>

#define TT 2048
#define DD 256
#define KK 1024
#define BB 16
#define NQ (BB*TT)   // 32768 queries per tensor

typedef __attribute__((ext_vector_type(8))) short short8;
typedef __attribute__((ext_vector_type(4))) short s16x4;
typedef __attribute__((ext_vector_type(4))) float f32x4;

#define AS1 __attribute__((address_space(1)))
#define AS3 __attribute__((address_space(3)))

__device__ __forceinline__ short bf16_rn(float x){
  unsigned u = __builtin_bit_cast(unsigned, x);
  unsigned r = u + 0x7fffu + ((u >> 16) & 1u);   // round-to-nearest-even
  return (short)(r >> 16);
}
__device__ __forceinline__ float bf16_to_f(short h){
  unsigned u = ((unsigned)(unsigned short)h) << 16;
  return __builtin_bit_cast(float, u);
}

// ---------------------------------------------------------------------------
// Fused prep: one wave per (tensor, code). Loads the fp32 row, emits the
// swizzled bf16 hi/lo codebook (4-short stores), 0.5*|e|^2, and zeroes
// counts/loss (replaces separate memset + 2 prep kernels).
// Swizzle: code k=(ct*16+c), dim d=(s*32+q*8+j) ->
//   pos = ((ct*8+s)*64 + (q*16+c))*8 + j   (1 KiB per (ct,s) block)
// ---------------------------------------------------------------------------
__global__ void vq_prep(const float* __restrict__ cb_top,
                        const float* __restrict__ cb_bot,
                        short* __restrict__ ws_cb,
                        float* __restrict__ e2h_all,
                        int* __restrict__ counts,
                        float* __restrict__ loss_acc){
  int gid = blockIdx.x*256 + threadIdx.x;          // 512 blocks -> 2048 waves
  int wv = gid >> 6, lane = gid & 63;
  int t = wv >> 10, k = wv & 1023;
  const float* row = (t ? cb_bot : cb_top) + (size_t)k*DD;
  f32x4 v = *(const f32x4*)(row + lane*4);
  float s2 = v[0]*v[0] + v[1]*v[1] + v[2]*v[2] + v[3]*v[3];
  s16x4 hi4, lo4;
  #pragma unroll
  for (int i = 0; i < 4; ++i){
    short hi = bf16_rn(v[i]);
    hi4[i] = hi;
    lo4[i] = bf16_rn(v[i] - bf16_to_f(hi));
  }
  const int d0 = lane*4;
  const int ct = k >> 4, c = k & 15;
  const int s = d0 >> 5, q = (d0 & 31) >> 3, j = d0 & 7;
  size_t pos = ((size_t)(ct*8 + s)*64 + (q*16 + c))*8 + j;   // j in {0,4}
  short* hib = ws_cb + (size_t)t * (2*KK*DD);
  *(s16x4*)(hib + pos) = hi4;
  *(s16x4*)(hib + (size_t)KK*DD + pos) = lo4;
  #pragma unroll
  for (int off = 1; off < 64; off <<= 1) s2 += __shfl_xor(s2, off, 64);
  if (lane == 0) e2h_all[t*KK + k] = 0.5f * s2;
  if (lane == 1) counts[t*KK + k] = 0;
  if (gid == 2) { loss_acc[0] = 0.f; loss_acc[1] = 0.f; }
}

// ---------------------------------------------------------------------------
// Stage one 32-code chunk (hi+lo, 32 KiB) into LDS: 8 x width-16
// global_load_lds per wave, 4 waves cover the 32 blocks of 1 KiB.
// ---------------------------------------------------------------------------
__device__ __forceinline__ void prefetch_chunk(const short* cbhi, const short* cblo,
                                               short* smem, int chunk, int w, int lane){
  #pragma unroll
  for (int k2 = 0; k2 < 8; ++k2){
    int bi = w*8 + k2;                              // 0..31
    int ctl = bi >> 4, rest = bi & 15, s = rest >> 1, hl = rest & 1;
    int ct = chunk*2 + ctl;
    const short* src = (hl ? cblo : cbhi) + (size_t)(ct*8 + s)*512 + lane*8;
    short* dst = smem + bi*512 + lane*8;
    __builtin_amdgcn_global_load_lds((AS1 void*)src, (AS3 void*)dst, 16, 0, 0);
  }
}

// ---------------------------------------------------------------------------
// Main: G=3 query groups per wave (48 queries), 3-term bf16-split MFMA argmin.
// grid (171, 2), block 256 (4 waves -> 192 queries/block; 64 pad queries).
// ---------------------------------------------------------------------------
__global__ __launch_bounds__(256, 2) void vq_main(
    const float* __restrict__ h_top, const float* __restrict__ h_bot,
    const float* __restrict__ cb_top, const float* __restrict__ cb_bot,
    const short* __restrict__ ws_cb, const float* __restrict__ e2h_all,
    int* __restrict__ counts, float* __restrict__ loss_acc,
    float* __restrict__ out)
{
  const int tz = blockIdx.y;
  const float* __restrict__ h   = tz ? h_bot : h_top;
  const float* __restrict__ cbf = tz ? cb_bot : cb_top;
  const short* cbhi = ws_cb + (size_t)tz * (2*KK*DD);
  const short* cblo = cbhi + KK*DD;
  const float* e2h = e2h_all + tz*KK;
  float* zout = out + (size_t)tz * ((size_t)NQ*DD);

  const int tid = threadIdx.x;
  const int w = tid >> 6, lane = tid & 63;
  const int c = lane & 15, q = lane >> 4;
  const int n0 = blockIdx.x*192 + w*48;             // first query of this wave

  __shared__ short smem[2][16384];                  // 2 x 32 KiB double buffer

  prefetch_chunk(cbhi, cblo, smem[0], 0, w, lane);

  // ---- prologue: 48 queries x 256 dims -> bf16 hi/lo B-fragments + |x|^2 ----
  short8 bhi[3][8], blo[3][8];
  float x2[3];
  #pragma unroll
  for (int g = 0; g < 3; ++g){
    int n = n0 + g*16 + c;
    if (n > NQ-1) n = NQ-1;                         // clamp pad queries
    const float* bp = h + (size_t)(n >> 11)*((size_t)DD*TT) + (n & (TT-1))
                        + (size_t)q*8*TT;
    float xs = 0.f;
    #pragma unroll
    for (int s = 0; s < 8; ++s){
      #pragma unroll
      for (int j = 0; j < 8; ++j){
        float v = bp[(size_t)(s*32 + j)*TT];        // d = s*32 + q*8 + j
        xs += v*v;
        short hi = bf16_rn(v);
        bhi[g][s][j] = hi;
        blo[g][s][j] = bf16_rn(v - bf16_to_f(hi));
      }
    }
    x2[g] = xs;
  }

  float bestv[3] = {3.4e38f, 3.4e38f, 3.4e38f};
  int   besti[3] = {0, 0, 0};

  __syncthreads();                                  // chunk 0 resident

  for (int chunk = 0; chunk < 32; ++chunk){
    const int buf = chunk & 1;
    if (chunk + 1 < 32) prefetch_chunk(cbhi, cblo, smem[buf^1], chunk+1, w, lane);
    const short* sb = smem[buf];
    #pragma unroll
    for (int ctl = 0; ctl < 2; ++ctl){
      f32x4 a0 = {0,0,0,0}, a1 = {0,0,0,0}, a2 = {0,0,0,0};
      #pragma unroll
      for (int s = 0; s < 8; ++s){
        short8 ahi = *(const short8*)(sb + (ctl*16 + s*2 + 0)*512 + lane*8);
        short8 alo = *(const short8*)(sb + (ctl*16 + s*2 + 1)*512 + lane*8);
        a0 = __builtin_amdgcn_mfma_f32_16x16x32_bf16(ahi, bhi[0][s], a0, 0,0,0);
        a1 = __builtin_amdgcn_mfma_f32_16x16x32_bf16(ahi, bhi[1][s], a1, 0,0,0);
        a2 = __builtin_amdgcn_mfma_f32_16x16x32_bf16(ahi, bhi[2][s], a2, 0,0,0);
        a0 = __builtin_amdgcn_mfma_f32_16x16x32_bf16(ahi, blo[0][s], a0, 0,0,0);
        a1 = __builtin_amdgcn_mfma_f32_16x16x32_bf16(ahi, blo[1][s], a1, 0,0,0);
        a2 = __builtin_amdgcn_mfma_f32_16x16x32_bf16(ahi, blo[2][s], a2, 0,0,0);
        a0 = __builtin_amdgcn_mfma_f32_16x16x32_bf16(alo, bhi[0][s], a0, 0,0,0);
        a1 = __builtin_amdgcn_mfma_f32_16x16x32_bf16(alo, bhi[1][s], a1, 0,0,0);
        a2 = __builtin_amdgcn_mfma_f32_16x16x32_bf16(alo, bhi[2][s], a2, 0,0,0);
      }
      const int code0 = chunk*32 + ctl*16 + q*4;    // C: row=code, col=query
      const f32x4 e2v = *(const f32x4*)(e2h + code0);
      #pragma unroll
      for (int r = 0; r < 4; ++r){
        float s0 = e2v[r] - a0[r];                  // = (dist - |x|^2)/2
        if (s0 < bestv[0]){ bestv[0] = s0; besti[0] = code0 + r; }
        float s1 = e2v[r] - a1[r];
        if (s1 < bestv[1]){ bestv[1] = s1; besti[1] = code0 + r; }
        float s2 = e2v[r] - a2[r];
        if (s2 < bestv[2]){ bestv[2] = s2; besti[2] = code0 + r; }
      }
    }
    __syncthreads();                                // drains prefetch + reuse guard
  }

  // ---- reduce across the 4 quads (codes are quad-partitioned) ----
  #pragma unroll
  for (int off = 16; off <= 32; off <<= 1){
    #pragma unroll
    for (int g = 0; g < 3; ++g){
      float ov = __shfl_xor(bestv[g], off, 64);
      int   oi = __shfl_xor(besti[g], off, 64);
      if (ov < bestv[g] || (ov == bestv[g] && oi < besti[g])){ bestv[g] = ov; besti[g] = oi; }
      x2[g] += __shfl_xor(x2[g], off, 64);
    }
  }

  // lane L < 48 owns query n0 + L  (g = L>>4, c = L&15)
  const int gsel = lane >> 4;
  const int n = n0 + lane;
  const bool valid = (lane < 48) && (n < NQ);
  float bv = (gsel == 0) ? bestv[0] : ((gsel == 1) ? bestv[1] : bestv[2]);
  int   bi = (gsel == 0) ? besti[0] : ((gsel == 1) ? besti[1] : besti[2]);
  float xx = (gsel == 0) ? x2[0]    : ((gsel == 1) ? x2[1]    : x2[2]);

  if (valid) atomicAdd(&counts[tz*KK + bi], 1);

  float ld = valid ? (xx + 2.0f*bv) : 0.0f;         // dist = |x|^2 + 2*score
  #pragma unroll
  for (int off = 1; off < 64; off <<= 1) ld += __shfl_xor(ld, off, 64);
  if (lane == 0) atomicAdd(&loss_acc[tz], ld);

  // ---- z = codebook[idx] in [B, D, T] layout (fp32 gather, L2-resident) ----
  if (valid){
    const float* crow = cbf + (size_t)bi * DD;
    float* zb = zout + (size_t)(n >> 11)*((size_t)DD*TT) + (n & (TT-1));
    #pragma unroll 4
    for (int d = 0; d < DD; d += 4){
      f32x4 cv = *(const f32x4*)(crow + d);
      zb[(size_t)(d+0)*TT] = cv[0];
      zb[(size_t)(d+1)*TT] = cv[1];
      zb[(size_t)(d+2)*TT] = cv[2];
      zb[(size_t)(d+3)*TT] = cv[3];
    }
  }
}

// ---------------------------------------------------------------------------
// Finalize: perplexities + loss scalars. outs = d_out + 2*NQ*DD.
// order: vq_loss, commitment_loss, ppl_top, ppl_bot
// ---------------------------------------------------------------------------
__global__ void vq_final(const int* __restrict__ counts,
                         const float* __restrict__ loss_acc,
                         float* __restrict__ outs){
  __shared__ float red[1024];
  const int tid = threadIdx.x;
  for (int t = 0; t < 2; ++t){
    float p = (float)counts[t*KK + tid] * (1.0f/(float)NQ);
    red[tid] = p * logf(p + 1e-10f);
    __syncthreads();
    for (int s = 512; s > 0; s >>= 1){
      if (tid < s) red[tid] += red[tid + s];
      __syncthreads();
    }
    if (tid == 0) outs[2 + t] = expf(-red[0]);
    __syncthreads();
  }
  if (tid == 0){
    float l = (loss_acc[0] + loss_acc[1]) * (1.0f/8388608.0f);  // mean over B*D*T
    outs[0] = l;   // vq_loss
    outs[1] = l;   // commitment_loss (same forward value)
  }
}

extern "C" void kernel_launch(void* const* d_in, const int* in_sizes, int n_in,
                              void* d_out, int out_size, void* d_ws, size_t ws_size,
                              hipStream_t stream)
{
  (void)in_sizes; (void)n_in; (void)out_size; (void)ws_size;
  const float* h_top  = (const float*)d_in[0];
  const float* h_bot  = (const float*)d_in[1];
  const float* cb_top = (const float*)d_in[2];
  const float* cb_bot = (const float*)d_in[3];
  float* out = (float*)d_out;
  char* ws = (char*)d_ws;

  short* ws_cb    = (short*)ws;                          // 2 MiB
  float* e2h      = (float*)(ws + (2u<<20));             // 8 KiB
  int*   counts   = (int*)  (ws + (2u<<20) + 8192);      // 8 KiB
  float* loss_acc = (float*)(ws + (2u<<20) + 16384);     // 8 B

  vq_prep<<<512, 256, 0, stream>>>(cb_top, cb_bot, ws_cb, e2h, counts, loss_acc);
  vq_main<<<dim3(171, 2), 256, 0, stream>>>(h_top, h_bot, cb_top, cb_bot,
                                            ws_cb, e2h, counts, loss_acc, out);
  vq_final<<<1, 1024, 0, stream>>>(counts, loss_acc, out + (size_t)2*NQ*DD);
}